// Round 2
// baseline (403.892 us; speedup 1.0000x reference)
//
#include <hip/hip_runtime.h>

// AdaMoeLayer: B=8,S=4096,D=512,E=8 -> T=32768 tokens
// Round 4 (resubmit; round-1 bench was an infra failure, no signal).
// Single-GEMM restructure. out = sum_e w[t,e]*(x@W_e) + sum_e w[t,e]*b_e
//   == (w-scaled A)[T x 4096] @ Bt[4096 x 512] with A[t, e*512+d] = w[t,e]*x[t,d].
// A is reg-staged from fp32 x (scale in fp32, ONE bf16 rounding -> same error as
// unscaled bf16(x) + fp32 fold). Single accumulator (no tmp/fold), 128x128 tile,
// double-buffered LDS, ONE barrier per K-step, prefetch issued before compute.

#define T_TOKENS 32768
#define DDIM 512
#define KDIM 4096

typedef __attribute__((ext_vector_type(8))) short short8;
typedef __attribute__((ext_vector_type(4))) float floatx4;
typedef __bf16 bf16x2 __attribute__((ext_vector_type(2)));

__device__ __forceinline__ unsigned short f2bf(float f) {
    unsigned int u = __float_as_uint(f);
    u += 0x7FFFu + ((u >> 16) & 1u);   // RNE
    return (unsigned short)(u >> 16);
}

__device__ __forceinline__ unsigned int pk2(float a, float b) {
#if __has_builtin(__builtin_amdgcn_cvt_pk_bf16_f32)
    bf16x2 v = __builtin_amdgcn_cvt_pk_bf16_f32(a, b);
    return __builtin_bit_cast(unsigned int, v);
#else
    return (unsigned int)f2bf(a) | ((unsigned int)f2bf(b) << 16);
#endif
}

__device__ __forceinline__ void async_copy16(const void* g, void* l) {
    __builtin_amdgcn_global_load_lds(
        (const __attribute__((address_space(1))) void*)g,
        (__attribute__((address_space(3))) void*)l, 16, 0, 0);
}

// ------- Kernel 1: gating (fp32) -> wbuf[T,8] ------------------------------
// 4 threads per token, shfl-xor reduce; grid = T/64 = 512 blocks.
__global__ __launch_bounds__(256) void gating(
    const float* __restrict__ x, const float* __restrict__ Wg,
    const float* __restrict__ bg, const float* __restrict__ Wt,
    const float* __restrict__ bt, float* __restrict__ wbuf)
{
    __shared__ float sW[512 * 12];  // [d][12]: e<8 gate cols, e==8 thr col
    const int tid = threadIdx.x;
    for (int i = tid; i < 512 * 9; i += 256) {
        int d = i / 9, e = i - d * 9;
        sW[d * 12 + e] = (e < 8) ? Wg[d * 8 + e] : Wt[d];
    }
    __syncthreads();

    const int t = blockIdx.x * 64 + (tid >> 2);
    const int q = tid & 3;
    float g[9];
#pragma unroll
    for (int e = 0; e < 9; ++e) g[e] = 0.f;

    const float4* xr = (const float4*)(x + (size_t)t * 512 + q * 128);
    for (int i = 0; i < 32; ++i) {
        float4 v = xr[i];
        float xv[4] = {v.x, v.y, v.z, v.w};
        const float* wp = &sW[(q * 128 + i * 4) * 12];
#pragma unroll
        for (int c = 0; c < 4; ++c) {
            const float* w = wp + c * 12;
#pragma unroll
            for (int e = 0; e < 9; ++e) g[e] = fmaf(xv[c], w[e], g[e]);
        }
    }
#pragma unroll
    for (int e = 0; e < 9; ++e) {
        g[e] += __shfl_xor(g[e], 1);
        g[e] += __shfl_xor(g[e], 2);
    }
    if (q == 0) {
#pragma unroll
        for (int e = 0; e < 8; ++e) g[e] += bg[e];
        g[8] += bt[0];
        float m = g[0];
#pragma unroll
        for (int e = 1; e < 8; ++e) m = fmaxf(m, g[e]);
        float s = 0.f;
        float p[8];
#pragma unroll
        for (int e = 0; e < 8; ++e) { p[e] = __expf(g[e] - m); s += p[e]; }
        const float inv = 1.f / s;
        const float thr = 0.25f / (1.f + __expf(-g[8]));
        float w8[8];
        float ws = 0.f;
#pragma unroll
        for (int e = 0; e < 8; ++e) {
            float a = p[e] * inv - thr;
            w8[e] = a > 0.f ? a : 0.f;
            ws += w8[e];
        }
        if (ws == 0.f) ws = 1.f;
        const float invw = 1.f / ws;
        float4 o0, o1;
        o0.x = w8[0] * invw; o0.y = w8[1] * invw; o0.z = w8[2] * invw; o0.w = w8[3] * invw;
        o1.x = w8[4] * invw; o1.y = w8[5] * invw; o1.z = w8[6] * invw; o1.w = w8[7] * invw;
        float4* op = (float4*)(wbuf + (size_t)t * 8);
        op[0] = o0;
        op[1] = o1;
    }
}

// ------------- Kernel 2: build Bt[512][4096] bf16 (transpose W_exp) --------
__global__ __launch_bounds__(256) void build_bt(
    const float* __restrict__ Wexp, unsigned short* __restrict__ Bt)
{
    __shared__ float tile[64][65];
    const int k0 = blockIdx.x * 64;
    const int n0 = blockIdx.y * 64;
    const int tid = threadIdx.x;
    const int r = tid >> 4, cq = tid & 15;
#pragma unroll
    for (int p = 0; p < 4; ++p) {
        const int rr = p * 16 + r;
        const float4 v = *(const float4*)(Wexp + (size_t)(k0 + rr) * 512 + n0 + cq * 4);
        tile[rr][cq * 4 + 0] = v.x;
        tile[rr][cq * 4 + 1] = v.y;
        tile[rr][cq * 4 + 2] = v.z;
        tile[rr][cq * 4 + 3] = v.w;
    }
    __syncthreads();
    const int rn = tid >> 2;  // output row (n), 0..63
    const int kq = tid & 3;   // 16-wide k chunk
    alignas(16) unsigned short buf[16];
#pragma unroll
    for (int j = 0; j < 16; ++j) buf[j] = f2bf(tile[kq * 16 + j][rn]);
    unsigned short* dst = Bt + (size_t)(n0 + rn) * KDIM + k0 + kq * 16;
    *(uint4*)(dst) = *(const uint4*)(buf);
    *(uint4*)(dst + 8) = *(const uint4*)(buf + 8);
}

// ------------- Kernel 3: main GEMM, 128x128 tile, K=4096, dbuf pipeline ----
// LDS tiles XOR-swizzled: element (row,k) at row*64 + ((k/8 ^ (row&7))*8)+k%8.
// A: reg-staged (fp32 x load -> w-scale -> pk_bf16 -> swizzled ds_write_b128).
// B: global_load_lds with lane->global chunk permutation cg = (lane&7)^(lane>>3).
// One __syncthreads per K-step: prefetch(s+1) issued BEFORE compute(s).
__global__ __launch_bounds__(256, 2) void moe_gemm(
    const float* __restrict__ x, const float* __restrict__ wbuf,
    const float* __restrict__ bexp, const unsigned short* __restrict__ Bt,
    float* __restrict__ out)
{
    __shared__ alignas(16) unsigned short As[2 * 128 * 64];  // 32 KB
    __shared__ alignas(16) unsigned short Bs[2 * 128 * 64];  // 32 KB
    __shared__ float sWb[128 * 8];                           // 4 KB gate weights
    __shared__ float sBb[8 * 128];                           // 4 KB bias slice

    const int tid = threadIdx.x;
    const int wave = tid >> 6;
    const int lane = tid & 63;
    const int wm = wave >> 1;   // 0..1: 64-row group
    const int wn = wave & 1;    // 0..1: 64-col group
    const int lm = lane & 15;
    const int lq = lane >> 4;
    const int brow = lane >> 3;
    const int cg = (lane & 7) ^ brow;  // lane->global chunk permutation (B)

    // A staging map: thread owns rows i*32 + ar (i=0..3), col chunk ac (8 cols)
    const int ar = tid >> 3;    // 0..31
    const int ac = tid & 7;     // chunk of 8 cols

    // XCD co-location: hw XCD = lin%8. Per XCD: 32 t-tiles x 4 n-tiles; the
    // 4 n-blocks of a t-tile are consecutive j (share x-slice in that L2).
    const int lin = blockIdx.x;
    const int g = lin & 7;
    const int j_ = lin >> 3;
    const int t0 = (g * 32 + (j_ >> 2)) * 128;
    const int n0 = (j_ & 3) * 128;

    ((float4*)sWb)[tid] = ((const float4*)(wbuf + (size_t)t0 * 8))[tid];
    ((float4*)sBb)[tid] = *(const float4*)(bexp + (size_t)(tid >> 5) * 512 + n0 + (tid & 31) * 4);
    __syncthreads();

    floatx4 acc[4][4];
#pragma unroll
    for (int i = 0; i < 4; ++i)
#pragma unroll
        for (int j = 0; j < 4; ++j) acc[i][j] = (floatx4){0.f, 0.f, 0.f, 0.f};

    float4 fa[8];
    float wv[4];

#define LOAD_A(d0)                                                              \
    {                                                                           \
        _Pragma("unroll")                                                       \
        for (int i = 0; i < 4; ++i) {                                           \
            const float4* xp = (const float4*)(x + (size_t)(t0 + i * 32 + ar) * 512 + (d0) + ac * 8); \
            fa[2 * i]     = xp[0];                                              \
            fa[2 * i + 1] = xp[1];                                              \
        }                                                                       \
    }

#define LOAD_W(e)                                                               \
    {                                                                           \
        _Pragma("unroll")                                                       \
        for (int i = 0; i < 4; ++i) wv[i] = sWb[(i * 32 + ar) * 8 + (e)];       \
    }

#define STAGE_B(ks, buf)                                                        \
    {                                                                           \
        _Pragma("unroll")                                                       \
        for (int i = 0; i < 4; ++i)                                             \
            async_copy16(Bt + (size_t)(n0 + wave * 32 + i * 8 + brow) * KDIM + (ks) * 64 + cg * 8, \
                         Bs + (buf) * 8192 + (wave * 32 + i * 8) * 64);         \
    }

#define WRITE_A(buf)                                                            \
    {                                                                           \
        _Pragma("unroll")                                                       \
        for (int i = 0; i < 4; ++i) {                                           \
            const int row = i * 32 + ar;                                        \
            const float w = wv[i];                                              \
            uint4 t;                                                            \
            t.x = pk2(w * fa[2 * i].x, w * fa[2 * i].y);                        \
            t.y = pk2(w * fa[2 * i].z, w * fa[2 * i].w);                        \
            t.z = pk2(w * fa[2 * i + 1].x, w * fa[2 * i + 1].y);                \
            t.w = pk2(w * fa[2 * i + 1].z, w * fa[2 * i + 1].w);                \
            *(uint4*)(As + (buf) * 8192 + row * 64 + ((ac ^ (row & 7)) << 3)) = t; \
        }                                                                       \
    }

    // prologue: stage step 0 into buffer 0
    LOAD_A(0);
    STAGE_B(0, 0);
    LOAD_W(0);
    WRITE_A(0);
    __syncthreads();

#pragma unroll 2
    for (int s = 0; s < 64; ++s) {
        const int nb = s & 1;
        // ---- prefetch step s+1 (A to regs, B direct to LDS) ----
        if (s < 63) {
            LOAD_A(((s + 1) & 7) << 6);
            STAGE_B(s + 1, nb ^ 1);
        }
        // ---- compute step s from buffer nb ----
        const unsigned short* Ab = As + nb * 8192;
        const unsigned short* Bb = Bs + nb * 8192;
#pragma unroll
        for (int kk = 0; kk < 2; ++kk) {
            const int ch = kk * 4 + lq;
            short8 a[4], b[4];
#pragma unroll
            for (int i = 0; i < 4; ++i) {
                const int row = wm * 64 + i * 16 + lm;
                a[i] = *(const short8*)(Ab + row * 64 + ((ch ^ (row & 7)) << 3));
            }
#pragma unroll
            for (int j = 0; j < 4; ++j) {
                const int row = wn * 64 + j * 16 + lm;
                b[j] = *(const short8*)(Bb + row * 64 + ((ch ^ (row & 7)) << 3));
            }
#pragma unroll
            for (int i = 0; i < 4; ++i)
#pragma unroll
                for (int j = 0; j < 4; ++j)
                    acc[i][j] = __builtin_amdgcn_mfma_f32_16x16x32_bf16(
                        a[i], b[j], acc[i][j], 0, 0, 0);
        }
        // ---- finish staging s+1: scale+cvt A, swizzled LDS write ----
        if (s < 63) {
            if (((s + 1) & 7) == 0) LOAD_W((s + 1) >> 3);
            WRITE_A(nb ^ 1);
        }
        __syncthreads();   // drains B global_load_lds (vmcnt) + A ds_writes
    }

    // epilogue: acc + sum_e w[t,e]*b_exp[e,col]; C/D: col=lane&15, row=lq*4+r
    float bc[4][8];
#pragma unroll
    for (int j = 0; j < 4; ++j) {
        const int coln = wn * 64 + j * 16 + lm;
#pragma unroll
        for (int e = 0; e < 8; ++e) bc[j][e] = sBb[e * 128 + coln];
    }
#pragma unroll
    for (int i = 0; i < 4; ++i)
#pragma unroll
        for (int r = 0; r < 4; ++r) {
            const int rowl = wm * 64 + i * 16 + lq * 4 + r;
            const float4 w0 = *(const float4*)(sWb + rowl * 8);
            const float4 w1 = *(const float4*)(sWb + rowl * 8 + 4);
            float* op = out + (size_t)(t0 + rowl) * 512 + n0 + wn * 64 + lm;
#pragma unroll
            for (int j = 0; j < 4; ++j) {
                float bias = w0.x * bc[j][0];
                bias = fmaf(w0.y, bc[j][1], bias);
                bias = fmaf(w0.z, bc[j][2], bias);
                bias = fmaf(w0.w, bc[j][3], bias);
                bias = fmaf(w1.x, bc[j][4], bias);
                bias = fmaf(w1.y, bc[j][5], bias);
                bias = fmaf(w1.z, bc[j][6], bias);
                bias = fmaf(w1.w, bc[j][7], bias);
                op[j * 16] = acc[i][j][r] + bias;
            }
        }
#undef LOAD_A
#undef LOAD_W
#undef STAGE_B
#undef WRITE_A
}

extern "C" void kernel_launch(void* const* d_in, const int* in_sizes, int n_in,
                              void* d_out, int out_size, void* d_ws, size_t ws_size,
                              hipStream_t stream) {
    const float* x   = (const float*)d_in[0];
    const float* Wg  = (const float*)d_in[1];
    const float* bg  = (const float*)d_in[2];
    const float* Wt  = (const float*)d_in[3];
    const float* bt  = (const float*)d_in[4];
    const float* Wex = (const float*)d_in[5];
    const float* bex = (const float*)d_in[6];
    float* out = (float*)d_out;

    // ws layout: Bt bf16 [512][4096] = 4 MB; wbuf fp32 [32768][8] = 1 MB.
    unsigned short* Bt = (unsigned short*)d_ws;
    float* wbuf = (float*)((char*)d_ws + (size_t)DDIM * KDIM * 2);

    gating<<<T_TOKENS / 64, 256, 0, stream>>>(x, Wg, bg, Wt, bt, wbuf);
    build_bt<<<dim3(KDIM / 64, DDIM / 64), 256, 0, stream>>>(Wex, Bt);
    moe_gemm<<<1024, 256, 0, stream>>>(x, wbuf, bex, Bt, out);
}

// Round 3
// 287.313 us; speedup vs baseline: 1.4058x; 1.4058x over previous
//
#include <hip/hip_runtime.h>

// AdaMoeLayer: B=8,S=4096,D=512,E=8 -> T=32768 tokens
// Round 5: merge R3 + R4 lessons.
//  - R3 numerics/staging: x -> bf16 Xbf once (gating kernel); GEMM stages BOTH
//    operands via global_load_lds width-16 (zero staging VALU); gate weight w
//    applied to the fp32 accumulator at expert boundaries (tmp/fold).
//  - R4 pipeline: 128x128 tile, double-buffered LDS, prefetch(s+1) issued
//    BEFORE compute(s), ONE __syncthreads per K-step. XOR-swizzled LDS.
// Expert e, k-step ks => global step s = e*8+ks (64 steps of BK=64).

#define T_TOKENS 32768
#define DDIM 512
#define KDIM 4096

typedef __attribute__((ext_vector_type(8))) short short8;
typedef __attribute__((ext_vector_type(4))) float floatx4;
typedef __bf16 bf16x2 __attribute__((ext_vector_type(2)));

__device__ __forceinline__ unsigned short f2bf(float f) {
    unsigned int u = __float_as_uint(f);
    u += 0x7FFFu + ((u >> 16) & 1u);   // RNE
    return (unsigned short)(u >> 16);
}

__device__ __forceinline__ unsigned int pk2(float a, float b) {
#if __has_builtin(__builtin_amdgcn_cvt_pk_bf16_f32)
    bf16x2 v = __builtin_amdgcn_cvt_pk_bf16_f32(a, b);
    return __builtin_bit_cast(unsigned int, v);
#else
    return (unsigned int)f2bf(a) | ((unsigned int)f2bf(b) << 16);
#endif
}

__device__ __forceinline__ void async_copy16(const void* g, void* l) {
    __builtin_amdgcn_global_load_lds(
        (const __attribute__((address_space(1))) void*)g,
        (__attribute__((address_space(3))) void*)l, 16, 0, 0);
}

// ------- Kernel 1: gating (fp32) -> wbuf[T,8]  +  x -> bf16 Xbf[T,512] ------
__global__ __launch_bounds__(256) void gating_cvt(
    const float* __restrict__ x, const float* __restrict__ Wg,
    const float* __restrict__ bg, const float* __restrict__ Wt,
    const float* __restrict__ bt, float* __restrict__ wbuf,
    unsigned short* __restrict__ Xbf)
{
    __shared__ float sW[512 * 12];  // [d][12]: e<8 gate cols, e==8 thr col
    const int tid = threadIdx.x;
    for (int i = tid; i < 512 * 9; i += 256) {
        int d = i / 9, e = i - d * 9;
        sW[d * 12 + e] = (e < 8) ? Wg[d * 8 + e] : Wt[d];
    }
    __syncthreads();

    const int t = blockIdx.x * 64 + (tid >> 2);
    const int q = tid & 3;
    float g[9];
#pragma unroll
    for (int e = 0; e < 9; ++e) g[e] = 0.f;

    const float4* xr = (const float4*)(x + (size_t)t * 512 + q * 128);
    for (int i = 0; i < 32; ++i) {
        float4 v = xr[i];
        float xv[4] = {v.x, v.y, v.z, v.w};
        const float* wp = &sW[(q * 128 + i * 4) * 12];
#pragma unroll
        for (int c = 0; c < 4; ++c) {
            const float* w = wp + c * 12;
#pragma unroll
            for (int e = 0; e < 9; ++e) g[e] = fmaf(xv[c], w[e], g[e]);
        }
    }
#pragma unroll
    for (int e = 0; e < 9; ++e) {
        g[e] += __shfl_xor(g[e], 1);
        g[e] += __shfl_xor(g[e], 2);
    }
    if (q == 0) {
#pragma unroll
        for (int e = 0; e < 8; ++e) g[e] += bg[e];
        g[8] += bt[0];
        float m = g[0];
#pragma unroll
        for (int e = 1; e < 8; ++e) m = fmaxf(m, g[e]);
        float s = 0.f;
        float p[8];
#pragma unroll
        for (int e = 0; e < 8; ++e) { p[e] = __expf(g[e] - m); s += p[e]; }
        const float inv = 1.f / s;
        const float thr = 0.25f / (1.f + __expf(-g[8]));
        float w8[8];
        float ws = 0.f;
#pragma unroll
        for (int e = 0; e < 8; ++e) {
            float a = p[e] * inv - thr;
            w8[e] = a > 0.f ? a : 0.f;
            ws += w8[e];
        }
        if (ws == 0.f) ws = 1.f;
        const float invw = 1.f / ws;
        float4 o0, o1;
        o0.x = w8[0] * invw; o0.y = w8[1] * invw; o0.z = w8[2] * invw; o0.w = w8[3] * invw;
        o1.x = w8[4] * invw; o1.y = w8[5] * invw; o1.z = w8[6] * invw; o1.w = w8[7] * invw;
        float4* op = (float4*)(wbuf + (size_t)t * 8);
        op[0] = o0;
        op[1] = o1;
    }

    // conversion pass: this block's 64 tokens = 32768 floats, coalesced (L2-hot)
    const size_t base = (size_t)blockIdx.x * 64 * 512;
    const float4* xs = (const float4*)(x + base);
    uint2* xd = (uint2*)(Xbf + base);
#pragma unroll 4
    for (int it = 0; it < 32; ++it) {
        float4 v = xs[it * 256 + tid];
        uint2 pk;
        pk.x = pk2(v.x, v.y);
        pk.y = pk2(v.z, v.w);
        xd[it * 256 + tid] = pk;
    }
}

// ------------- Kernel 2: build Bt[512][4096] bf16 (transpose W_exp) --------
__global__ __launch_bounds__(256) void build_bt(
    const float* __restrict__ Wexp, unsigned short* __restrict__ Bt)
{
    __shared__ float tile[64][65];
    const int k0 = blockIdx.x * 64;
    const int n0 = blockIdx.y * 64;
    const int tid = threadIdx.x;
    const int r = tid >> 4, cq = tid & 15;
#pragma unroll
    for (int p = 0; p < 4; ++p) {
        const int rr = p * 16 + r;
        const float4 v = *(const float4*)(Wexp + (size_t)(k0 + rr) * 512 + n0 + cq * 4);
        tile[rr][cq * 4 + 0] = v.x;
        tile[rr][cq * 4 + 1] = v.y;
        tile[rr][cq * 4 + 2] = v.z;
        tile[rr][cq * 4 + 3] = v.w;
    }
    __syncthreads();
    const int rn = tid >> 2;  // output row (n), 0..63
    const int kq = tid & 3;   // 16-wide k chunk
    alignas(16) unsigned short buf[16];
#pragma unroll
    for (int j = 0; j < 16; ++j) buf[j] = f2bf(tile[kq * 16 + j][rn]);
    unsigned short* dst = Bt + (size_t)(n0 + rn) * KDIM + k0 + kq * 16;
    *(uint4*)(dst) = *(const uint4*)(buf);
    *(uint4*)(dst + 8) = *(const uint4*)(buf + 8);
}

// ------------- Kernel 3: main GEMM, 128x128 tile, expert fold, dbuf --------
// LDS tiles XOR-swizzled: element (row,k) at row*64 + ((k/8 ^ (row&7))*8)+k%8.
// Both operands staged by global_load_lds with lane->global chunk permutation
// cg = (lane&7)^(lane>>3) so data lands pre-swizzled (zero staging VALU).
__global__ __launch_bounds__(256, 2) void moe_gemm(
    const unsigned short* __restrict__ Xbf, const float* __restrict__ wbuf,
    const float* __restrict__ bexp, const unsigned short* __restrict__ Bt,
    float* __restrict__ out)
{
    __shared__ alignas(16) unsigned short As[2 * 128 * 64];  // 32 KB
    __shared__ alignas(16) unsigned short Bs[2 * 128 * 64];  // 32 KB
    __shared__ float sWbT[8 * 128];                          // 4 KB, [e][row]
    __shared__ float sBb[8 * 128];                           // 4 KB, [e][col]

    const int tid = threadIdx.x;
    const int wave = tid >> 6;
    const int lane = tid & 63;
    const int wm = wave >> 1;   // 0..1: 64-row group
    const int wn = wave & 1;    // 0..1: 64-col group
    const int lm = lane & 15;
    const int lq = lane >> 4;
    const int brow = lane >> 3;
    const int cg = (lane & 7) ^ brow;  // lane->global chunk permutation

    // XCD co-location: hw XCD = lin%8. Per XCD: 32 t-tiles x 4 n-tiles; the
    // 4 n-blocks of a t-tile are consecutive j (share Xbf slice in that L2).
    const int lin = blockIdx.x;
    const int g = lin & 7;
    const int j_ = lin >> 3;
    const int t0 = (g * 32 + (j_ >> 2)) * 128;
    const int n0 = (j_ & 3) * 128;

    // sWbT[e][row] = wbuf[t0+row][e]  (transposed so fold reads are b128)
    {
        const int row = tid >> 1, half = tid & 1;
        const float4 wv4 = *(const float4*)(wbuf + (size_t)(t0 + row) * 8 + half * 4);
        sWbT[(half * 4 + 0) * 128 + row] = wv4.x;
        sWbT[(half * 4 + 1) * 128 + row] = wv4.y;
        sWbT[(half * 4 + 2) * 128 + row] = wv4.z;
        sWbT[(half * 4 + 3) * 128 + row] = wv4.w;
    }
    ((float4*)sBb)[tid] = *(const float4*)(bexp + (size_t)(tid >> 5) * 512 + n0 + (tid & 31) * 4);

#define STAGE_A(d0, buf)                                                        \
    {                                                                           \
        _Pragma("unroll")                                                       \
        for (int i = 0; i < 4; ++i)                                             \
            async_copy16(Xbf + (size_t)(t0 + wave * 32 + i * 8 + brow) * 512 + (d0) + cg * 8, \
                         As + (buf) * 8192 + (wave * 32 + i * 8) * 64);         \
    }

#define STAGE_B(k0, buf)                                                        \
    {                                                                           \
        _Pragma("unroll")                                                       \
        for (int i = 0; i < 4; ++i)                                             \
            async_copy16(Bt + (size_t)(n0 + wave * 32 + i * 8 + brow) * KDIM + (k0) + cg * 8, \
                         Bs + (buf) * 8192 + (wave * 32 + i * 8) * 64);         \
    }

    // prologue: stage step 0 into buffer 0 (also covers sWbT/sBb ds_writes)
    STAGE_A(0, 0);
    STAGE_B(0, 0);
    __syncthreads();

    floatx4 acc[4][4], tmp[4][4];
#pragma unroll
    for (int i = 0; i < 4; ++i)
#pragma unroll
        for (int j = 0; j < 4; ++j) acc[i][j] = (floatx4){0.f, 0.f, 0.f, 0.f};

    // tmp init for expert 0: bias splat per column (C/D col = lane&15)
#pragma unroll
    for (int j = 0; j < 4; ++j) {
        const float bb = sBb[0 * 128 + wn * 64 + j * 16 + lm];
#pragma unroll
        for (int i = 0; i < 4; ++i) tmp[i][j] = (floatx4){bb, bb, bb, bb};
    }

#pragma unroll 2
    for (int s = 0; s < 64; ++s) {
        const int nb = s & 1;
        // ---- prefetch step s+1 into buffer nb^1 ----
        if (s < 63) {
            STAGE_A((((s + 1) & 7) << 6), nb ^ 1);
            STAGE_B(((s + 1) << 6), nb ^ 1);
        }
        // ---- compute step s from buffer nb ----
        const unsigned short* Ab = As + nb * 8192;
        const unsigned short* Bb = Bs + nb * 8192;
#pragma unroll
        for (int kk = 0; kk < 2; ++kk) {
            const int ch = kk * 4 + lq;
            short8 a[4], b[4];
#pragma unroll
            for (int i = 0; i < 4; ++i) {
                const int row = wm * 64 + i * 16 + lm;
                a[i] = *(const short8*)(Ab + row * 64 + ((ch ^ (row & 7)) << 3));
            }
#pragma unroll
            for (int j = 0; j < 4; ++j) {
                const int row = wn * 64 + j * 16 + lm;
                b[j] = *(const short8*)(Bb + row * 64 + ((ch ^ (row & 7)) << 3));
            }
#pragma unroll
            for (int i = 0; i < 4; ++i)
#pragma unroll
                for (int j = 0; j < 4; ++j)
                    tmp[i][j] = __builtin_amdgcn_mfma_f32_16x16x32_bf16(
                        a[i], b[j], tmp[i][j], 0, 0, 0);
        }
        // ---- expert boundary: fold acc += w[t,e]*tmp, reinit tmp ----
        if ((s & 7) == 7) {
            const int e = s >> 3;
#pragma unroll
            for (int i = 0; i < 4; ++i) {
                const float4 wq = *(const float4*)(sWbT + e * 128 + wm * 64 + i * 16 + lq * 4);
#pragma unroll
                for (int j = 0; j < 4; ++j) {
                    acc[i][j][0] = fmaf(wq.x, tmp[i][j][0], acc[i][j][0]);
                    acc[i][j][1] = fmaf(wq.y, tmp[i][j][1], acc[i][j][1]);
                    acc[i][j][2] = fmaf(wq.z, tmp[i][j][2], acc[i][j][2]);
                    acc[i][j][3] = fmaf(wq.w, tmp[i][j][3], acc[i][j][3]);
                }
            }
            if (s < 63) {
#pragma unroll
                for (int j = 0; j < 4; ++j) {
                    const float bb = sBb[(e + 1) * 128 + wn * 64 + j * 16 + lm];
#pragma unroll
                    for (int i = 0; i < 4; ++i) tmp[i][j] = (floatx4){bb, bb, bb, bb};
                }
            }
        }
        __syncthreads();   // drains global_load_lds (vmcnt) for buffer nb^1
    }

    // epilogue: C/D layout col=lane&15, row=(lane>>4)*4+reg
#pragma unroll
    for (int i = 0; i < 4; ++i)
#pragma unroll
        for (int r = 0; r < 4; ++r) {
            const int rowl = wm * 64 + i * 16 + lq * 4 + r;
            float* op = out + (size_t)(t0 + rowl) * 512 + n0 + wn * 64 + lm;
#pragma unroll
            for (int j = 0; j < 4; ++j) op[j * 16] = acc[i][j][r];
        }
#undef STAGE_A
#undef STAGE_B
}

extern "C" void kernel_launch(void* const* d_in, const int* in_sizes, int n_in,
                              void* d_out, int out_size, void* d_ws, size_t ws_size,
                              hipStream_t stream) {
    const float* x   = (const float*)d_in[0];
    const float* Wg  = (const float*)d_in[1];
    const float* bg  = (const float*)d_in[2];
    const float* Wt  = (const float*)d_in[3];
    const float* bt  = (const float*)d_in[4];
    const float* Wex = (const float*)d_in[5];
    const float* bex = (const float*)d_in[6];
    float* out = (float*)d_out;

    // ws layout: Xbf bf16 [32768][512] = 32 MB; Bt bf16 [512][4096] = 4 MB;
    //            wbuf fp32 [32768][8] = 1 MB.  Total 37 MB.
    unsigned short* Xbf = (unsigned short*)d_ws;
    unsigned short* Bt  = (unsigned short*)((char*)d_ws + (size_t)T_TOKENS * DDIM * 2);
    float* wbuf = (float*)((char*)d_ws + (size_t)T_TOKENS * DDIM * 2
                                       + (size_t)DDIM * KDIM * 2);

    gating_cvt<<<T_TOKENS / 64, 256, 0, stream>>>(x, Wg, bg, Wt, bt, wbuf, Xbf);
    build_bt<<<dim3(KDIM / 64, DDIM / 64), 256, 0, stream>>>(Wex, Bt);
    moe_gemm<<<1024, 256, 0, stream>>>(Xbf, wbuf, bex, Bt, out);
}